// Round 5
// baseline (108.426 us; speedup 1.0000x reference)
//
#include <hip/hip_runtime.h>

typedef __bf16 bf16;
typedef __attribute__((ext_vector_type(4))) bf16 bf16x4;
typedef __attribute__((ext_vector_type(8))) bf16 bf16x8;
typedef __attribute__((ext_vector_type(4))) float f32x4;
typedef __attribute__((ext_vector_type(2))) float f32x2;

namespace {

constexpr int NITERS = 50;   // R11 ERRATUM: ref's 50-iter iterate is NOT the
                             // fixed point; count must match exactly.
constexpr int KEXACT = 16;   // updates 0..15 use exact v_rcp (trans pipe —
                             // overlaps VALU); 16..49 use one Newton step.

// ---- compile-time physical constants (double) ----
constexpr double csqrt(double x) {
  double s = x > 1 ? x : 1;
  for (int i = 0; i < 60; ++i) s = 0.5 * (s + x / s);
  return s;
}
constexpr double AP_D =
    ((3.667 - 1.0) / (3.667 + 0.5)) * (0.3 * (7.5 * csqrt(7.5)) / 0.0002395);
constexpr double RGAST_D = (8.3144598 / 4184.0) * 623.15;

__device__ __forceinline__ float sss_val(int i, int j) {
  // SSS[i][j] = exp(-DELTAW/(RGAS*T)); symmetric; zero outside 51x51 (pad)
  if (i > 50 || j > 50) return 0.0f;
  const float si = -0.025f + 0.001f * (float)i;
  const float sj = -0.025f + 0.001f * (float)j;
  const float acc = fmaxf(0.0f, fmaxf(si, sj) - 0.0084f);
  const float don = fminf(0.0f, fminf(si, sj) + 0.0084f);
  const float dw = (float)(AP_D * 0.5) * (si + sj) * (si + sj) + 85580.0f * acc * don;
  return expf(-dw * (float)(1.0 / RGAST_D));
}

// Row-slot -> actual sigma-row. Slots 0..47 = rows 0..47. The 3 remaining
// real rows (48,49,50) live in tile-3 class r=0 (slots 48,52,56 = g 0..2);
// ALL of classes (tp=3, r>=1) are pad.
__device__ __forceinline__ int slot2row(int slot) {
  if (slot < 48) return slot;
  if ((slot & 3) == 0 && slot < 60) return 48 + ((slot - 48) >> 2);
  return 99;   // pad -> sss_val 0 / load 0
}

__device__ __forceinline__ float fast_log(float x) {
  return __builtin_amdgcn_logf(x) * 0.69314718056f;   // ln via log2
}

// HW-verified gfx950 shape (guide §3; R4/R5/R8/R9 passed with it).
__device__ __forceinline__ f32x4 mfma(bf16x8 a, bf16x8 b, f32x4 c) {
  return __builtin_amdgcn_mfma_f32_16x16x32_bf16(a, b, c, 0, 0, 0);
}

} // namespace

// R5 = R1 launch shape x R4 body. One wave = ONE chain of 16 solves
// (8 elements x {pure,mix}); 4 waves/SIMD (grid B/32, launch_bounds(256,4))
// provide the latency coverage R4's 2 waves lacked, while the R4-lean body
// (f32x2 pairs, 13-element trim, rotated schedule) keeps the issue bill low.
// Rotated schedule: update(d_k) ; cvtb ; matvec -> d_{k+1}, so the MFMA at
// the back edge is covered by the other 3 waves' update phases.
__global__ __launch_bounds__(256, 4) void cosmo_mfma_r5(
    const float* __restrict__ my_sigma,   // [B,51]
    const float* __restrict__ v_comp,     // [B]
    const float* __restrict__ vt_sigma,   // [B,51,2]
    const float* __restrict__ v_vt,       // [B]
    float* __restrict__ out,              // [B]
    int B)
{
  const int lane = threadIdx.x & 63;
  const int wv   = threadIdx.x >> 6;
  const int s    = lane & 15;     // solve slot (C col / A-frag m pos)
  const int g    = lane >> 4;     // lane group 0..3
  const int task = s & 1;         // 0 = pure, 1 = mix
  const int e    = blockIdx.x * 32 + wv * 8 + (s >> 1);
  const bool ein = (e < B);
  const int  ec  = ein ? e : 0;

  // ---- prologue: rows owned by this lane (slot = 16t+4g+r) ----
  float A0, A1;
  f32x2 wh2[6], Gt2[6];           // 12 live elements tiles 0-2 as pairs
  float wh12, Gt12;               // + 1 (tile3, r0)
  {
    float myv[13], vtv[13];
#pragma unroll
    for (int t = 0; t < 4; ++t)
#pragma unroll
      for (int r = 0; r < 4; ++r) {
        const int li = 4 * t + r;
        if (li >= 13) continue;                  // tile3 r>=1: dead
        const int n  = slot2row(16 * t + 4 * g + r);
        const bool nv = (n < 51) && ein;
        const int nc = (n < 51) ? n : 50;
        myv[li] = nv ? my_sigma[(size_t)ec * 51 + nc] : 0.0f;
        vtv[li] = nv ? vt_sigma[((size_t)ec * 51 + nc) * 2 + 1] : 0.0f;
      }
    float pA0 = 0.f, pA1 = 0.f;
#pragma unroll
    for (int i = 0; i < 13; ++i) { pA0 += myv[i]; pA1 += vtv[i]; }
    pA0 += __shfl_xor(pA0, 16, 64); pA0 += __shfl_xor(pA0, 32, 64);
    pA1 += __shfl_xor(pA1, 16, 64); pA1 += __shfl_xor(pA1, 32, 64);
    A0 = pA0; A1 = pA1;

    const float den  = task ? (0.235f * pA0 + 0.765f * pA1) : pA0;
    const float rden = __builtin_amdgcn_rcpf(den);
    const float rdh  = 0.5f * rden;
    float w[13], wh[13];
#pragma unroll
    for (int i = 0; i < 13; ++i) {
      const float num = task ? (0.235f * myv[i] + 0.765f * vtv[i]) : myv[i];
      w[i]  = num * rden;    // psigma of this task; 0 on pads
      wh[i] = num * rdh;     // 0.5 * psigma (damped-update coefficient)
    }
#pragma unroll
    for (int p = 0; p < 6; ++p) {
      wh2[p][0] = wh[2 * p]; wh2[p][1] = wh[2 * p + 1];
      Gt2[p][0] = w[2 * p];  Gt2[p][1] = w[2 * p + 1];   // init G = 1
    }
    wh12 = wh[12]; Gt12 = w[12];
  }

  // ---- constant A fragments (k-permuted, row-remapped):
  //      afr[tp][kt][i] = S[row(16tp+s)][row(16*(2kt+(i>>2)) + 4g + (i&3))] ----
  bf16x8 afr[4][2];
#pragma unroll
  for (int tp = 0; tp < 4; ++tp)
#pragma unroll
    for (int kt = 0; kt < 2; ++kt) {
      bf16x8 v;
#pragma unroll
      for (int i = 0; i < 8; ++i) {
        const int kslot = 16 * (2 * kt + (i >> 2)) + 4 * g + (i & 3);
        v[i] = (bf16)sss_val(slot2row(16 * tp + s), slot2row(kslot));
      }
      afr[tp][kt] = v;
    }

  // tile-3 acc init: element 0 slot = 48+4g -> pad iff g==3 (+1 -> d=1).
  f32x4 pad3;
  pad3[0] = (g == 3) ? 1.0f : 0.0f;
  pad3[1] = pad3[2] = pad3[3] = 1.0f;

  const bf16 bz = (bf16)0.0f;

  f32x2 rc2[6];                  // running 1/d per element pair
  float rc12 = 1.0f;
#pragma unroll
  for (int p = 0; p < 6; ++p) { rc2[p][0] = 1.0f; rc2[p][1] = 1.0f; }

  bf16x8 b0, b1;
  f32x4  acc[4];

  // cvtb: Gt (f32 pairs) -> bf16 B-fragments (pairs map onto v_cvt_pk dwords)
  auto cvtb = [&]() {
    bf16x8 t0, t1;
#pragma unroll
    for (int p = 0; p < 4; ++p) {
      t0[2 * p]     = (bf16)Gt2[p][0];
      t0[2 * p + 1] = (bf16)Gt2[p][1];
    }
    t1[0] = (bf16)Gt2[4][0]; t1[1] = (bf16)Gt2[4][1];
    t1[2] = (bf16)Gt2[5][0]; t1[3] = (bf16)Gt2[5][1];
    t1[4] = (bf16)Gt12; t1[5] = bz; t1[6] = bz; t1[7] = bz;
    b0 = t0; b1 = t1;
  };

  auto matvec = [&]() {
    const f32x4 z = {};
#pragma unroll
    for (int tp = 0; tp < 3; ++tp) acc[tp] = mfma(afr[tp][0], b0, z);
    acc[3] = mfma(afr[3][0], b0, pad3);
#pragma unroll
    for (int tp = 0; tp < 4; ++tp) acc[tp] = mfma(afr[tp][1], b1, acc[tp]);
  };

  auto upd_rcp = [&]() {
#pragma unroll
    for (int tp = 0; tp < 3; ++tp)
#pragma unroll
      for (int h = 0; h < 2; ++h) {
        const int p = 2 * tp + h;
        f32x2 rc;
        rc[0] = __builtin_amdgcn_rcpf(acc[tp][2 * h]);
        rc[1] = __builtin_amdgcn_rcpf(acc[tp][2 * h + 1]);
        rc2[p] = rc;
        Gt2[p] = 0.5f * Gt2[p] + wh2[p] * rc;
      }
    rc12 = __builtin_amdgcn_rcpf(acc[3][0]);
    Gt12 = 0.5f * Gt12 + wh12 * rc12;
  };

  auto upd_newton = [&]() {
#pragma unroll
    for (int tp = 0; tp < 3; ++tp)
#pragma unroll
      for (int h = 0; h < 2; ++h) {
        const int p = 2 * tp + h;
        f32x2 d;
        d[0] = acc[tp][2 * h]; d[1] = acc[tp][2 * h + 1];
        const f32x2 nr = 2.0f - d * rc2[p];
        const f32x2 rc = rc2[p] * nr;
        rc2[p] = rc;
        Gt2[p] = 0.5f * Gt2[p] + wh2[p] * rc;
      }
    {
      const float nr = 2.0f - acc[3][0] * rc12;
      rc12 = rc12 * nr;
      Gt12 = 0.5f * Gt12 + wh12 * rc12;
    }
  };

  // ---- rotated pipeline: d_0 in the prologue; update k consumes d_k and
  //      the following matvec computes d_{k+1} ----
  cvtb(); matvec();

  // phase 1: exact reciprocal updates 0..KEXACT-1 (seeds Newton)
#pragma unroll 1
  for (int it = 0; it < KEXACT; ++it) {
    upd_rcp(); cvtb(); matvec();
  }
  // phase 2: Newton updates KEXACT..NITERS-2
#pragma unroll 1
  for (int it = KEXACT; it < NITERS - 1; ++it) {
    upd_newton(); cvtb(); matvec();
  }
  // final update (d_49) — no further matvec
  upd_newton();

  // ---- epilogue: S_task = sum_n psigma_pure[n] * ln(G[n]), G = Gt/w ----
  const float rA0 = __builtin_amdgcn_rcpf(A0);
  float Sp = 0.f;
#pragma unroll
  for (int t = 0; t < 4; ++t)
#pragma unroll
    for (int r = 0; r < 4; ++r) {
      const int li = 4 * t + r;
      if (li >= 13) continue;
      const int n = slot2row(16 * t + 4 * g + r);
      if (n < 51) {
        const float whv = (li < 12) ? wh2[li >> 1][li & 1] : wh12;
        const float gtv = (li < 12) ? Gt2[li >> 1][li & 1] : Gt12;
        const float p  = (ein ? my_sigma[(size_t)ec * 51 + n] : 0.0f) * rA0;
        // guard w==0 (exact-0 input): p==0 there, force ln arg -> 1
        // G = Gt/w = Gt * rcp(2*wh) = Gt * 0.5 * rcp(wh)
        const float gg = (whv != 0.0f)
                           ? gtv * (0.5f * __builtin_amdgcn_rcpf(whv)) : 1.0f;
        Sp += p * __builtin_amdgcn_logf(gg);
      }
    }
  Sp += __shfl_xor(Sp, 16, 64);
  Sp += __shfl_xor(Sp, 32, 64);
  const float St = Sp * 0.69314718056f;
  const float So = __shfl_xor(St, 1, 64);   // partner task's sum

  if (task == 0 && g == 0 && ein) {
    const float lng_resid = A0 * (1.0f / 7.5f) * (So - St);
    const float v0  = v_comp[e];
    const float v1v = v_vt[e];
    const float q0 = A0 * (1.0f / 79.53f), q1 = A1 * (1.0f / 79.53f);
    const float r0 = v0 * (1.0f / 66.69f), r1 = v1v * (1.0f / 66.69f);
    const float xq = 0.235f * q0 + 0.765f * q1;
    const float xr = 0.235f * r0 + 0.765f * r1;
    const float theta = 0.235f * q0 * __builtin_amdgcn_rcpf(xq);
    const float phi   = 0.235f * r0 * __builtin_amdgcn_rcpf(xr);
    const float l0 = 5.0f * (r0 - q0) - (r0 - 1.0f);
    const float l1 = 5.0f * (r1 - q1) - (r1 - 1.0f);
    const float xl = 0.235f * l0 + 0.765f * l1;
    const float lng_comb = fast_log(phi * (1.0f / 0.235f))
                         + 5.0f * q0 * fast_log(theta * __builtin_amdgcn_rcpf(phi))
                         + l0 - (phi * (1.0f / 0.235f)) * xl;
    out[e] = lng_resid + lng_comb;
  }
}

extern "C" void kernel_launch(void* const* d_in, const int* in_sizes, int n_in,
                              void* d_out, int out_size, void* d_ws, size_t ws_size,
                              hipStream_t stream) {
  const float* my  = (const float*)d_in[0];
  const float* vc  = (const float*)d_in[1];
  const float* vts = (const float*)d_in[2];
  const float* vvt = (const float*)d_in[3];
  float* out = (float*)d_out;
  const int B = in_sizes[1];                    // v_compound is [B]
  const int grid = (B + 31) / 32;               // 32 elements per 256-thread block
  cosmo_mfma_r5<<<grid, 256, 0, stream>>>(my, vc, vts, vvt, out, B);
}